// Round 1
// baseline (62.058 us; speedup 1.0000x reference)
//
#include <hip/hip_runtime.h>

constexpr int Bdim = 8192;
constexpr int Ddim = 256;
constexpr int TILE = 256;
constexpr int NT   = Bdim / TILE;           // 32 tiles per side
constexpr int NTRI = NT * (NT + 1) / 2;     // 528 upper-tri tiles
constexpr int RCH  = 4;                     // row chunks per tile
constexpr int RPC  = TILE / RCH;            // 64 rows per chunk
constexpr int NPART = NTRI * RCH;           // 2112 partials
constexpr float MARGIN_F = 0.1f;

// d(x,0) = 2*artanh(||x||) = log((1+n)/(1-n)), one wave per row
__global__ __launch_bounds__(256) void k_norm(const float* __restrict__ emb,
                                              float* __restrict__ d) {
    int row  = blockIdx.x * 4 + (threadIdx.x >> 6);
    int lane = threadIdx.x & 63;
    float4 v = ((const float4*)(emb + (size_t)row * Ddim))[lane];
    float s = v.x * v.x + v.y * v.y + v.z * v.z + v.w * v.w;
#pragma unroll
    for (int off = 32; off > 0; off >>= 1) s += __shfl_down(s, off, 64);
    if (lane == 0) {
        float n = fminf(sqrtf(s), 1.0f - 1e-5f);
        d[row] = logf((1.0f + n) / (1.0f - n));
    }
}

// Upper-triangular tile reduction over cmp. Each block: one 256-wide tile,
// one 64-row chunk. Coalesced int loads; per-block partial sum/count.
__global__ __launch_bounds__(256) void k_pairs(const float* __restrict__ d,
                                               const int* __restrict__ cmp,
                                               double* __restrict__ psum,
                                               unsigned int* __restrict__ pcnt) {
    // decode linear triangular tile index -> (ti, tj), tj >= ti
    int rem = blockIdx.x;
    int ti = 0;
    while (rem >= NT - ti) { rem -= NT - ti; ++ti; }
    int tj = ti + rem;

    int tid = threadIdx.x;
    int j = tj * TILE + tid;
    float dj = d[j];

    __shared__ float dis[RPC];
    int i0 = ti * TILE + blockIdx.y * RPC;
    if (tid < RPC) dis[tid] = d[i0 + tid];
    __syncthreads();

    float s = 0.0f;
    int cnt = 0;
    const int* p = cmp + i0 * Bdim + j;
    if (ti == tj) {
        for (int r = 0; r < RPC; ++r) {
            int i = i0 + r;
            if (j > i) {
                int c = p[r * Bdim];
                if (c != 0) {
                    // c==-1: relu(d_i-d_j+m); c==+1: relu(d_j-d_i+m)
                    float x = fmaf((float)c, dj - dis[r], MARGIN_F);
                    s += fmaxf(x, 0.0f);
                    ++cnt;
                }
            }
        }
    } else {
#pragma unroll 4
        for (int r = 0; r < RPC; ++r) {
            int c = p[r * Bdim];
            if (c != 0) {
                float x = fmaf((float)c, dj - dis[r], MARGIN_F);
                s += fmaxf(x, 0.0f);
                ++cnt;
            }
        }
    }

#pragma unroll
    for (int off = 32; off > 0; off >>= 1) {
        s   += __shfl_down(s, off, 64);
        cnt += __shfl_down(cnt, off, 64);
    }
    __shared__ float ws_s[4];
    __shared__ int   ws_c[4];
    int wave = tid >> 6;
    if ((tid & 63) == 0) { ws_s[wave] = s; ws_c[wave] = cnt; }
    __syncthreads();
    if (tid == 0) {
        float st = ws_s[0] + ws_s[1] + ws_s[2] + ws_s[3];
        int   ct = ws_c[0] + ws_c[1] + ws_c[2] + ws_c[3];
        int slot = blockIdx.y * NTRI + blockIdx.x;
        psum[slot] = (double)st;
        pcnt[slot] = (unsigned int)ct;
    }
}

__global__ __launch_bounds__(256) void k_final(const double* __restrict__ psum,
                                               const unsigned int* __restrict__ pcnt,
                                               float* __restrict__ out) {
    int tid = threadIdx.x;
    double s = 0.0;
    unsigned long long c = 0;
    for (int idx = tid; idx < NPART; idx += 256) {
        s += psum[idx];
        c += pcnt[idx];
    }
#pragma unroll
    for (int off = 32; off > 0; off >>= 1) {
        s += __shfl_down(s, off, 64);
        c += __shfl_down(c, off, 64);
    }
    __shared__ double sd[4];
    __shared__ unsigned long long sc[4];
    int wave = tid >> 6;
    if ((tid & 63) == 0) { sd[wave] = s; sc[wave] = c; }
    __syncthreads();
    if (tid == 0) {
        double st = sd[0] + sd[1] + sd[2] + sd[3];
        unsigned long long ct = sc[0] + sc[1] + sc[2] + sc[3];
        out[0] = (ct > 0) ? (float)(st / (double)ct) : 0.0f;
    }
}

extern "C" void kernel_launch(void* const* d_in, const int* in_sizes, int n_in,
                              void* d_out, int out_size, void* d_ws, size_t ws_size,
                              hipStream_t stream) {
    const float* emb = (const float*)d_in[0];
    const int*   cmp = (const int*)d_in[1];
    float* out = (float*)d_out;

    char* ws = (char*)d_ws;
    float*        dvec = (float*)ws;                         // 8192 * 4 = 32768 B
    double*       psum = (double*)(ws + 32768);              // 2112 * 8 = 16896 B
    unsigned int* pcnt = (unsigned int*)(ws + 32768 + NPART * 8); // 2112 * 4 B

    hipLaunchKernelGGL(k_norm, dim3(Bdim / 4), dim3(256), 0, stream, emb, dvec);
    hipLaunchKernelGGL(k_pairs, dim3(NTRI, RCH), dim3(256), 0, stream,
                       dvec, cmp, psum, pcnt);
    hipLaunchKernelGGL(k_final, dim3(1), dim3(256), 0, stream, psum, pcnt, out);
}

// Round 2
// 36.947 us; speedup vs baseline: 1.6797x; 1.6797x over previous
//
#include <hip/hip_runtime.h>

constexpr int Bdim = 8192;
constexpr int Ddim = 256;
constexpr int TILE = 256;                   // tile width in columns
constexpr int NT   = Bdim / TILE;           // 32 tiles per side
constexpr int NTRI = NT * (NT + 1) / 2;     // 528 upper-tri tiles
constexpr int RCH  = 4;                     // row chunks per tile
constexpr int RPC  = TILE / RCH;            // 64 rows per chunk
constexpr int RPW  = RPC / 4;               // 16 rows per wave
constexpr int NPART = NTRI * RCH;           // 2112 partials
constexpr float MARGIN_F = 0.1f;

// d(x,0) = 2*artanh(||x||) = log((1+n)/(1-n)), one wave per row
__global__ __launch_bounds__(256) void k_norm(const float* __restrict__ emb,
                                              float* __restrict__ d) {
    int row  = blockIdx.x * 4 + (threadIdx.x >> 6);
    int lane = threadIdx.x & 63;
    float4 v = ((const float4*)(emb + (size_t)row * Ddim))[lane];
    float s = v.x * v.x + v.y * v.y + v.z * v.z + v.w * v.w;
#pragma unroll
    for (int off = 32; off > 0; off >>= 1) s += __shfl_down(s, off, 64);
    if (lane == 0) {
        float n = fminf(sqrtf(s), 1.0f - 1e-5f);
        d[row] = logf((1.0f + n) / (1.0f - n));
    }
}

// Upper-triangular tile reduction over cmp.
// Block = 256 threads = 4 waves. Each wave owns a contiguous 16-row strip of a
// 64-row x 256-col tile chunk. Each lane loads int4 (4 columns, 16B) per row:
// 1 KiB per wave-load. Interior is branchless (cndmask only).
__global__ __launch_bounds__(256) void k_pairs(const float* __restrict__ d,
                                               const int* __restrict__ cmp,
                                               double* __restrict__ psum,
                                               unsigned int* __restrict__ pcnt) {
    // decode linear triangular tile index -> (ti, tj), tj >= ti
    int rem = blockIdx.x;
    int ti = 0;
    while (rem >= NT - ti) { rem -= NT - ti; ++ti; }
    int tj = ti + rem;

    int tid  = threadIdx.x;
    int lane = tid & 63;
    int wave = tid >> 6;

    int j0 = tj * TILE + lane * 4;                  // 4 consecutive columns
    float4 dj = *(const float4*)(d + j0);

    __shared__ float dis[RPC];
    int i0 = ti * TILE + blockIdx.y * RPC;
    if (tid < RPC) dis[tid] = d[i0 + tid];
    __syncthreads();

    int rbase = wave * RPW;                          // 0,16,32,48
    const int4* p = (const int4*)(cmp + (size_t)(i0 + rbase) * Bdim + j0);

    float s = 0.0f;
    int cnt = 0;

    if (ti == tj) {
        // diagonal tile: per-element j > i predicate (branchless)
#pragma unroll 4
        for (int r = 0; r < RPW; ++r) {
            int   i  = i0 + rbase + r;
            float di = dis[rbase + r];
            int4  c  = p[(size_t)r * (Bdim / 4)];
            {
                bool act = (c.x != 0) & (j0 + 0 > i);
                float x = fmaf((float)c.x, dj.x - di, MARGIN_F);
                s += act ? fmaxf(x, 0.0f) : 0.0f; cnt += act ? 1 : 0;
            }
            {
                bool act = (c.y != 0) & (j0 + 1 > i);
                float x = fmaf((float)c.y, dj.y - di, MARGIN_F);
                s += act ? fmaxf(x, 0.0f) : 0.0f; cnt += act ? 1 : 0;
            }
            {
                bool act = (c.z != 0) & (j0 + 2 > i);
                float x = fmaf((float)c.z, dj.z - di, MARGIN_F);
                s += act ? fmaxf(x, 0.0f) : 0.0f; cnt += act ? 1 : 0;
            }
            {
                bool act = (c.w != 0) & (j0 + 3 > i);
                float x = fmaf((float)c.w, dj.w - di, MARGIN_F);
                s += act ? fmaxf(x, 0.0f) : 0.0f; cnt += act ? 1 : 0;
            }
        }
    } else {
#pragma unroll 4
        for (int r = 0; r < RPW; ++r) {
            float di = dis[rbase + r];
            int4  c  = p[(size_t)r * (Bdim / 4)];
            {
                bool act = (c.x != 0);
                float x = fmaf((float)c.x, dj.x - di, MARGIN_F);
                s += act ? fmaxf(x, 0.0f) : 0.0f; cnt += act ? 1 : 0;
            }
            {
                bool act = (c.y != 0);
                float x = fmaf((float)c.y, dj.y - di, MARGIN_F);
                s += act ? fmaxf(x, 0.0f) : 0.0f; cnt += act ? 1 : 0;
            }
            {
                bool act = (c.z != 0);
                float x = fmaf((float)c.z, dj.z - di, MARGIN_F);
                s += act ? fmaxf(x, 0.0f) : 0.0f; cnt += act ? 1 : 0;
            }
            {
                bool act = (c.w != 0);
                float x = fmaf((float)c.w, dj.w - di, MARGIN_F);
                s += act ? fmaxf(x, 0.0f) : 0.0f; cnt += act ? 1 : 0;
            }
        }
    }

#pragma unroll
    for (int off = 32; off > 0; off >>= 1) {
        s   += __shfl_down(s, off, 64);
        cnt += __shfl_down(cnt, off, 64);
    }
    __shared__ float ws_s[4];
    __shared__ int   ws_c[4];
    if ((tid & 63) == 0) { ws_s[wave] = s; ws_c[wave] = cnt; }
    __syncthreads();
    if (tid == 0) {
        float st = ws_s[0] + ws_s[1] + ws_s[2] + ws_s[3];
        int   ct = ws_c[0] + ws_c[1] + ws_c[2] + ws_c[3];
        int slot = blockIdx.y * NTRI + blockIdx.x;
        psum[slot] = (double)st;
        pcnt[slot] = (unsigned int)ct;
    }
}

__global__ __launch_bounds__(256) void k_final(const double* __restrict__ psum,
                                               const unsigned int* __restrict__ pcnt,
                                               float* __restrict__ out) {
    int tid = threadIdx.x;
    double s = 0.0;
    unsigned long long c = 0;
    for (int idx = tid; idx < NPART; idx += 256) {
        s += psum[idx];
        c += pcnt[idx];
    }
#pragma unroll
    for (int off = 32; off > 0; off >>= 1) {
        s += __shfl_down(s, off, 64);
        c += __shfl_down(c, off, 64);
    }
    __shared__ double sd[4];
    __shared__ unsigned long long sc[4];
    int wave = tid >> 6;
    if ((tid & 63) == 0) { sd[wave] = s; sc[wave] = c; }
    __syncthreads();
    if (tid == 0) {
        double st = sd[0] + sd[1] + sd[2] + sd[3];
        unsigned long long ct = sc[0] + sc[1] + sc[2] + sc[3];
        out[0] = (ct > 0) ? (float)(st / (double)ct) : 0.0f;
    }
}

extern "C" void kernel_launch(void* const* d_in, const int* in_sizes, int n_in,
                              void* d_out, int out_size, void* d_ws, size_t ws_size,
                              hipStream_t stream) {
    const float* emb = (const float*)d_in[0];
    const int*   cmp = (const int*)d_in[1];
    float* out = (float*)d_out;

    char* ws = (char*)d_ws;
    float*        dvec = (float*)ws;                              // 8192 * 4 B
    double*       psum = (double*)(ws + 32768);                   // 2112 * 8 B
    unsigned int* pcnt = (unsigned int*)(ws + 32768 + NPART * 8); // 2112 * 4 B

    hipLaunchKernelGGL(k_norm, dim3(Bdim / 4), dim3(256), 0, stream, emb, dvec);
    hipLaunchKernelGGL(k_pairs, dim3(NTRI, RCH), dim3(256), 0, stream,
                       dvec, cmp, psum, pcnt);
    hipLaunchKernelGGL(k_final, dim3(1), dim3(256), 0, stream, psum, pcnt, out);
}

// Round 4
// 35.917 us; speedup vs baseline: 1.7278x; 1.0287x over previous
//
#include <hip/hip_runtime.h>

constexpr int Bdim = 8192;
constexpr int Ddim = 256;
constexpr int TILE = 256;                   // tile width in columns
constexpr int NT   = Bdim / TILE;           // 32 tiles per side
constexpr int NTRI = NT * (NT + 1) / 2;     // 528 upper-tri tiles
constexpr int RCH  = 8;                     // row chunks per tile
constexpr int RPC  = TILE / RCH;            // 32 rows per chunk (one unit)
constexpr int RPW  = RPC / 4;               // 8 rows per wave
constexpr int NUNIT = NTRI * RCH;           // 4224 units
constexpr int NBLK  = 2048;                 // exactly 8 blocks/CU
constexpr float MARGIN_F = 0.1f;

typedef int iv4 __attribute__((ext_vector_type(4)));   // native vector for
                                                       // __builtin_nontemporal_load

// d(x,0) = 2*artanh(||x||) = log((1+n)/(1-n)), one wave per row
__global__ __launch_bounds__(256) void k_norm(const float* __restrict__ emb,
                                              float* __restrict__ d) {
    int row  = blockIdx.x * 4 + (threadIdx.x >> 6);
    int lane = threadIdx.x & 63;
    float4 v = ((const float4*)(emb + (size_t)row * Ddim))[lane];
    float s = v.x * v.x + v.y * v.y + v.z * v.z + v.w * v.w;
#pragma unroll
    for (int off = 32; off > 0; off >>= 1) s += __shfl_down(s, off, 64);
    if (lane == 0) {
        float n = fminf(sqrtf(s), 1.0f - 1e-5f);
        d[row] = logf((1.0f + n) / (1.0f - n));
    }
}

// Grid-stride over 4224 units (32 rows x 256 cols each). Block = 4 waves;
// each wave owns an 8-row strip, each lane an iv4 (4 cols). Non-temporal
// loads for the zero-reuse cmp stream; branchless interior.
__global__ __launch_bounds__(256) void k_pairs(const float* __restrict__ d,
                                               const int* __restrict__ cmp,
                                               double* __restrict__ psum,
                                               unsigned int* __restrict__ pcnt) {
    int tid  = threadIdx.x;
    int lane = tid & 63;
    int wave = tid >> 6;

    float s = 0.0f;
    int cnt = 0;

    for (int u = blockIdx.x; u < NUNIT; u += NBLK) {
        int tri   = u % NTRI;
        int chunk = u / NTRI;
        // decode triangular tile index -> (ti, tj), tj >= ti
        int rem = tri, ti = 0;
        while (rem >= NT - ti) { rem -= NT - ti; ++ti; }
        int tj = ti + rem;

        int i0 = ti * TILE + chunk * RPC + wave * RPW;   // this wave's 8 rows
        int j0 = tj * TILE + lane * 4;                   // 4 consecutive cols
        float4 dj = *(const float4*)(d + j0);
        const iv4* p = (const iv4*)(cmp + (size_t)i0 * Bdim + j0);

        if (ti == tj) {
            // diagonal tile: lanes entirely at/below the diagonal skip the
            // fetch (exec-masked -> whole cache lines not read)
            if (j0 + 3 > i0) {
#pragma unroll
                for (int r = 0; r < RPW; ++r) {
                    int   i  = i0 + r;
                    float di = d[i];
                    iv4   c  = __builtin_nontemporal_load(p);
                    p += Bdim / 4;
                    {
                        bool act = (c.x != 0) & (j0 + 0 > i);
                        float x = fmaf((float)c.x, dj.x - di, MARGIN_F);
                        s += act ? fmaxf(x, 0.0f) : 0.0f; cnt += act ? 1 : 0;
                    }
                    {
                        bool act = (c.y != 0) & (j0 + 1 > i);
                        float x = fmaf((float)c.y, dj.y - di, MARGIN_F);
                        s += act ? fmaxf(x, 0.0f) : 0.0f; cnt += act ? 1 : 0;
                    }
                    {
                        bool act = (c.z != 0) & (j0 + 2 > i);
                        float x = fmaf((float)c.z, dj.z - di, MARGIN_F);
                        s += act ? fmaxf(x, 0.0f) : 0.0f; cnt += act ? 1 : 0;
                    }
                    {
                        bool act = (c.w != 0) & (j0 + 3 > i);
                        float x = fmaf((float)c.w, dj.w - di, MARGIN_F);
                        s += act ? fmaxf(x, 0.0f) : 0.0f; cnt += act ? 1 : 0;
                    }
                }
            }
        } else {
#pragma unroll 4
            for (int r = 0; r < RPW; ++r) {
                float di = d[i0 + r];
                iv4   c  = __builtin_nontemporal_load(p);
                p += Bdim / 4;
                {
                    bool act = (c.x != 0);
                    float x = fmaf((float)c.x, dj.x - di, MARGIN_F);
                    s += act ? fmaxf(x, 0.0f) : 0.0f; cnt += act ? 1 : 0;
                }
                {
                    bool act = (c.y != 0);
                    float x = fmaf((float)c.y, dj.y - di, MARGIN_F);
                    s += act ? fmaxf(x, 0.0f) : 0.0f; cnt += act ? 1 : 0;
                }
                {
                    bool act = (c.z != 0);
                    float x = fmaf((float)c.z, dj.z - di, MARGIN_F);
                    s += act ? fmaxf(x, 0.0f) : 0.0f; cnt += act ? 1 : 0;
                }
                {
                    bool act = (c.w != 0);
                    float x = fmaf((float)c.w, dj.w - di, MARGIN_F);
                    s += act ? fmaxf(x, 0.0f) : 0.0f; cnt += act ? 1 : 0;
                }
            }
        }
    }

#pragma unroll
    for (int off = 32; off > 0; off >>= 1) {
        s   += __shfl_down(s, off, 64);
        cnt += __shfl_down(cnt, off, 64);
    }
    __shared__ float ws_s[4];
    __shared__ int   ws_c[4];
    if ((tid & 63) == 0) { ws_s[wave] = s; ws_c[wave] = cnt; }
    __syncthreads();
    if (tid == 0) {
        float st = ws_s[0] + ws_s[1] + ws_s[2] + ws_s[3];
        int   ct = ws_c[0] + ws_c[1] + ws_c[2] + ws_c[3];
        psum[blockIdx.x] = (double)st;
        pcnt[blockIdx.x] = (unsigned int)ct;
    }
}

__global__ __launch_bounds__(256) void k_final(const double* __restrict__ psum,
                                               const unsigned int* __restrict__ pcnt,
                                               float* __restrict__ out) {
    int tid = threadIdx.x;
    double s = 0.0;
    unsigned long long c = 0;
    for (int idx = tid; idx < NBLK; idx += 256) {
        s += psum[idx];
        c += pcnt[idx];
    }
#pragma unroll
    for (int off = 32; off > 0; off >>= 1) {
        s += __shfl_down(s, off, 64);
        c += __shfl_down(c, off, 64);
    }
    __shared__ double sd[4];
    __shared__ unsigned long long sc[4];
    int wave = tid >> 6;
    if ((tid & 63) == 0) { sd[wave] = s; sc[wave] = c; }
    __syncthreads();
    if (tid == 0) {
        double st = sd[0] + sd[1] + sd[2] + sd[3];
        unsigned long long ct = sc[0] + sc[1] + sc[2] + sc[3];
        out[0] = (ct > 0) ? (float)(st / (double)ct) : 0.0f;
    }
}

extern "C" void kernel_launch(void* const* d_in, const int* in_sizes, int n_in,
                              void* d_out, int out_size, void* d_ws, size_t ws_size,
                              hipStream_t stream) {
    const float* emb = (const float*)d_in[0];
    const int*   cmp = (const int*)d_in[1];
    float* out = (float*)d_out;

    char* ws = (char*)d_ws;
    float*        dvec = (float*)ws;                              // 8192 * 4 B
    double*       psum = (double*)(ws + 32768);                   // 2048 * 8 B
    unsigned int* pcnt = (unsigned int*)(ws + 32768 + NBLK * 8);  // 2048 * 4 B

    hipLaunchKernelGGL(k_norm, dim3(Bdim / 4), dim3(256), 0, stream, emb, dvec);
    hipLaunchKernelGGL(k_pairs, dim3(NBLK), dim3(256), 0, stream,
                       dvec, cmp, psum, pcnt);
    hipLaunchKernelGGL(k_final, dim3(1), dim3(256), 0, stream, psum, pcnt, out);
}